// Round 2
// baseline (126.617 us; speedup 1.0000x reference)
//
#include <hip/hip_runtime.h>

typedef __attribute__((ext_vector_type(8))) short bf16x8;
typedef __attribute__((ext_vector_type(4))) float f32x4;
typedef unsigned short u16;

#define D_MODEL 1024
#define ROWS 32            // rows per block (was 64): grid 512, 4 blocks/CU

// Packed-weight geometry: fragments of 512 bf16 (64 lanes x 8), frag(nt,kt).
// Phase-1 B: 17 col-tiles (16 down + 1 gate-padded) x 32 k-tiles (K=1024).
// Phase-2 B: 64 col-tiles (N=1024)                x  8 k-tiles (K=256).
#define WD_FRAGS (17 * 32)
#define WU_FRAGS (64 * 8)
#define WD_ELEMS (WD_FRAGS * 512)   // 278528 bf16
#define WU_ELEMS (WU_FRAGS * 512)   // 262144 bf16

__device__ __forceinline__ u16 f2bf(float f) {  // RNE f32 -> bf16
  union { float f; unsigned u; } v; v.f = f;
  return (u16)((v.u + 0x7fffu + ((v.u >> 16) & 1u)) >> 16);
}

// Pack per-expert weights into MFMA B-fragment order (bf16).
// Fragment element (lane, j) holds B[k = kt*32 + (lane>>4)*8 + j][col = nt*16 + (lane&15)].
__global__ void lora_prep(const float* __restrict__ Wd, const float* __restrict__ Wu,
                          const float* __restrict__ Wg,
                          u16* __restrict__ wd_pack, u16* __restrict__ wu_pack) {
  int idx = blockIdx.x * 256 + threadIdx.x;
  if (idx < WD_ELEMS) {
    int frag = idx >> 9, w = idx & 511;
    int lane = w >> 3, j = w & 7;
    int nt = frag >> 5, kt = frag & 31;
    int k = kt * 32 + (lane >> 4) * 8 + j;        // 0..1023
    int col = nt * 16 + (lane & 15);              // 0..271
    float v;
    if (col < 256) {
      v = Wd[((col >> 6) * 1024 + k) * 64 + (col & 63)];   // W_down[e][k][a]
    } else {
      int c2 = col - 256;
      v = (c2 < 4) ? Wg[k * 4 + c2] : 0.f;                 // W_gate[k][e], zero-padded
    }
    wd_pack[idx] = f2bf(v);
  } else if (idx < WD_ELEMS + WU_ELEMS) {
    int u = idx - WD_ELEMS;
    int frag = u >> 9, w = u & 511;
    int lane = w >> 3, j = w & 7;
    int nt = frag >> 3, kt = frag & 7;
    int k = kt * 32 + (lane >> 4) * 8 + j;        // 0..255 (= e*64 + a)
    int col = nt * 16 + (lane & 15);              // 0..1023
    wu_pack[u] = f2bf(Wu[((k >> 6) * 64 + (k & 63)) * 1024 + col]);  // W_up[e][a][d]
  }
}

// LDS chunk tile: [32 rows][256 k] bf16, row stride 512 B, XOR-swizzled:
// byte = row*512 + (2*k ^ ((row&7)<<4))  -> ds_read_b128 A-frags are ~2-way (free).
__device__ __forceinline__ void pack_store(char* dst, int r, int col, float4 v0, float4 v1) {
  bf16x8 h;
  h[0] = (short)f2bf(v0.x); h[1] = (short)f2bf(v0.y);
  h[2] = (short)f2bf(v0.z); h[3] = (short)f2bf(v0.w);
  h[4] = (short)f2bf(v1.x); h[5] = (short)f2bf(v1.y);
  h[6] = (short)f2bf(v1.z); h[7] = (short)f2bf(v1.w);
  int cb = col * 2;
  *(bf16x8*)(dst + r * 512 + (cb ^ ((r & 7) << 4))) = h;
}

// LDS map: buf0 [0,16384) | buf1 [16384,32768) | g[32][4] f32 [32768,33280)
__global__ __launch_bounds__(256, 4) void lora_main(
    const float* __restrict__ x, const float* __restrict__ b_gate,
    const u16* __restrict__ wd_pack, const u16* __restrict__ wu_pack,
    float* __restrict__ out) {
  extern __shared__ char smem[];
  float* g = (float*)(smem + 32768);

  const int tid = threadIdx.x;
  const int lane = tid & 63;
  const int wave = tid >> 6;       // 4 waves
  const int l15 = lane & 15;
  const int lg = lane >> 4;
  const size_t row0 = (size_t)blockIdx.x * ROWS;
  const float* xblk = x + row0 * D_MODEL;

  f32x4 acc[4][2];   // [col-tile i][row-frag r]; wave w owns tiles {w, w+4, w+8, w+12}
  f32x4 accg[2];     // gate tile (nt=16), wave 3 only
#pragma unroll
  for (int i = 0; i < 4; ++i)
#pragma unroll
    for (int r = 0; r < 2; ++r) acc[i][r] = {0.f, 0.f, 0.f, 0.f};
#pragma unroll
  for (int r = 0; r < 2; ++r) accg[r] = {0.f, 0.f, 0.f, 0.f};

  // ---- prologue: stage K-chunk 0 into buf0 (fp32 -> bf16, swizzled)
  {
    const float* src = xblk;
#pragma unroll
    for (int it = 0; it < 4; ++it) {
      int flat = it * 2048 + tid * 8;        // 32 rows x 256 cols = 8192 floats
      int r = flat >> 8, col = flat & 255;
      float4 v0 = *(const float4*)(src + r * D_MODEL + col);
      float4 v1 = *(const float4*)(src + r * D_MODEL + col + 4);
      pack_store(smem, r, col, v0, v1);
    }
  }
  __syncthreads();

  // ---- phase 1: down[32][256] (+gate logits), K = 1024 in 4 chunks of 256
  float4 pre[8];
#pragma unroll 1
  for (int c = 0; c < 4; ++c) {
    if (c < 3) {  // T14 split: issue next chunk's global loads before compute
      const float* src = xblk + (c + 1) * 256;
#pragma unroll
      for (int it = 0; it < 4; ++it) {
        int flat = it * 2048 + tid * 8;
        int r = flat >> 8, col = flat & 255;
        pre[2 * it]     = *(const float4*)(src + r * D_MODEL + col);
        pre[2 * it + 1] = *(const float4*)(src + r * D_MODEL + col + 4);
      }
    }
    const char* buf = smem + (c & 1) * 16384;
#pragma unroll
    for (int ks = 0; ks < 8; ++ks) {
      const int ktg = c * 8 + ks;
      bf16x8 a[2];
#pragma unroll
      for (int r = 0; r < 2; ++r) {
        int rr = r * 16 + l15;
        int cb = (ks * 32 + lg * 8) * 2;
        a[r] = *(const bf16x8*)(buf + rr * 512 + (cb ^ ((rr & 7) << 4)));
      }
#pragma unroll
      for (int i = 0; i < 4; ++i) {
        const int nt = wave + i * 4;
        bf16x8 b = *(const bf16x8*)(wd_pack + (size_t)(nt * 32 + ktg) * 512 + lane * 8);
#pragma unroll
        for (int r = 0; r < 2; ++r)
          acc[i][r] = __builtin_amdgcn_mfma_f32_16x16x32_bf16(a[r], b, acc[i][r], 0, 0, 0);
      }
      if (wave == 3) {  // gate tile nt=16 -> frag base 16*32 = 512
        bf16x8 b = *(const bf16x8*)(wd_pack + (size_t)(512 + ktg) * 512 + lane * 8);
#pragma unroll
        for (int r = 0; r < 2; ++r)
          accg[r] = __builtin_amdgcn_mfma_f32_16x16x32_bf16(a[r], b, accg[r], 0, 0, 0);
      }
    }
    if (c < 3) {  // write-late: convert + ds_write into the other buffer
      char* dst = smem + ((c + 1) & 1) * 16384;
#pragma unroll
      for (int it = 0; it < 4; ++it) {
        int flat = it * 2048 + tid * 8;
        int r = flat >> 8, col = flat & 255;
        pack_store(dst, r, col, pre[2 * it], pre[2 * it + 1]);
      }
    }
    __syncthreads();
  }

  // ---- gate softmax (fp32). C-layout: col=lane&15, row=(lane>>4)*4+reg.
  if (wave == 3 && l15 < 4) {
#pragma unroll
    for (int r = 0; r < 2; ++r)
#pragma unroll
      for (int j = 0; j < 4; ++j)
        g[(r * 16 + lg * 4 + j) * 4 + l15] = accg[r][j];
  }
  __syncthreads();
  if (tid < ROWS) {
    float v0 = g[tid * 4 + 0] + b_gate[0];
    float v1 = g[tid * 4 + 1] + b_gate[1];
    float v2 = g[tid * 4 + 2] + b_gate[2];
    float v3 = g[tid * 4 + 3] + b_gate[3];
    float m = fmaxf(fmaxf(v0, v1), fmaxf(v2, v3));
    float e0 = expf(v0 - m), e1 = expf(v1 - m), e2 = expf(v2 - m), e3 = expf(v3 - m);
    float inv = 1.f / (e0 + e1 + e2 + e3);
    g[tid * 4 + 0] = e0 * inv; g[tid * 4 + 1] = e1 * inv;
    g[tid * 4 + 2] = e2 * inv; g[tid * 4 + 3] = e3 * inv;
  }
  __syncthreads();

  // ---- apply gate, pack down to bf16 into buf0 (same swizzled layout, k=ea)
  char* ds = smem;
#pragma unroll
  for (int i = 0; i < 4; ++i) {
    int nt = wave + i * 4;
    int col = nt * 16 + l15;
    int e = nt >> 2;              // 4 col-tiles per expert
    int cb = col * 2;
#pragma unroll
    for (int r = 0; r < 2; ++r) {
#pragma unroll
      for (int j = 0; j < 4; ++j) {
        int row = r * 16 + lg * 4 + j;
        float val = acc[i][r][j] * g[row * 4 + e];
        *(u16*)(ds + row * 512 + (cb ^ ((row & 7) << 4))) = f2bf(val);
      }
    }
  }
  __syncthreads();

  // ---- phase 2: out[32][1024] = down_g[32][256] @ Wup, N in 4 chunks of 256
#pragma unroll 1
  for (int nc = 0; nc < 4; ++nc) {
    f32x4 acc2[4][2];
#pragma unroll
    for (int i = 0; i < 4; ++i)
#pragma unroll
      for (int r = 0; r < 2; ++r) acc2[i][r] = {0.f, 0.f, 0.f, 0.f};
#pragma unroll
    for (int ks = 0; ks < 8; ++ks) {
      bf16x8 a[2];
#pragma unroll
      for (int r = 0; r < 2; ++r) {
        int rr = r * 16 + l15;
        int cb = (ks * 32 + lg * 8) * 2;
        a[r] = *(const bf16x8*)(ds + rr * 512 + (cb ^ ((rr & 7) << 4)));
      }
#pragma unroll
      for (int i = 0; i < 4; ++i) {
        int ntu = nc * 16 + wave * 4 + i;
        bf16x8 b = *(const bf16x8*)(wu_pack + (size_t)(ntu * 8 + ks) * 512 + lane * 8);
#pragma unroll
        for (int r = 0; r < 2; ++r)
          acc2[i][r] = __builtin_amdgcn_mfma_f32_16x16x32_bf16(a[r], b, acc2[i][r], 0, 0, 0);
      }
    }
#pragma unroll
    for (int i = 0; i < 4; ++i) {
      int col = (nc * 16 + wave * 4 + i) * 16 + l15;
#pragma unroll
      for (int r = 0; r < 2; ++r)
#pragma unroll
        for (int j = 0; j < 4; ++j) {
          int row = r * 16 + lg * 4 + j;
          out[(row0 + row) * D_MODEL + col] = acc2[i][r][j];
        }
    }
  }
}

extern "C" void kernel_launch(void* const* d_in, const int* in_sizes, int n_in,
                              void* d_out, int out_size, void* d_ws, size_t ws_size,
                              hipStream_t stream) {
  const float* x  = (const float*)d_in[0];
  const float* Wd = (const float*)d_in[1];
  const float* Wu = (const float*)d_in[2];
  const float* Wg = (const float*)d_in[3];
  const float* bg = (const float*)d_in[4];
  float* out = (float*)d_out;
  const int M = in_sizes[0] / D_MODEL;  // 16384

  u16* wd_pack = (u16*)d_ws;            // 557056 B
  u16* wu_pack = wd_pack + WD_ELEMS;    // +524288 B  (needs ~1.03 MB of ws)

  const int total = WD_ELEMS + WU_ELEMS;
  lora_prep<<<(total + 255) / 256, 256, 0, stream>>>(Wd, Wu, Wg, wd_pack, wu_pack);
  lora_main<<<M / ROWS, 256, 33280, stream>>>(x, bg, wd_pack, wu_pack, out);
}

// Round 4
// 73.295 us; speedup vs baseline: 1.7275x; 1.7275x over previous
//
#include <hip/hip_runtime.h>

typedef __attribute__((ext_vector_type(8))) short bf16x8;
typedef __attribute__((ext_vector_type(4))) float f32x4;
typedef unsigned short u16;

#define D_MODEL 1024
#define ROWS 32            // rows per block: grid 512, 2 blocks/CU

// Packed-weight geometry: fragments of 512 bf16 (64 lanes x 8), frag(nt,kt).
// Phase-1 B: 17 col-tiles (16 down + 1 gate-padded) x 32 k-tiles (K=1024).
// Phase-2 B: 64 col-tiles (N=1024)                x  8 k-tiles (K=256).
#define WD_FRAGS (17 * 32)
#define WU_FRAGS (64 * 8)
#define WD_ELEMS (WD_FRAGS * 512)   // 278528 bf16
#define WU_ELEMS (WU_FRAGS * 512)   // 262144 bf16

// LDS map (bytes), total 49664:
//  phase 1: buf0 [0,16384) | buf1 [16384,32768) | g[32][4] f32 [32768,33280)
//  phase 2: ds (gated-down, 32x512B) = buf0 [0,16384)
//           tb (transpose, 32x260 f32 = 33280 B) = [16384,49664)  (buf1+g dead)
#define LDS_TOTAL 49664
#define TB_STRIDE 260

__device__ __forceinline__ u16 f2bf(float f) {  // RNE f32 -> bf16
  union { float f; unsigned u; } v; v.f = f;
  return (u16)((v.u + 0x7fffu + ((v.u >> 16) & 1u)) >> 16);
}

// Pack per-expert weights into MFMA B-fragment order (bf16).
// Fragment element (lane, j) holds B[k = kt*32 + (lane>>4)*8 + j][col = nt*16 + (lane&15)].
__global__ void lora_prep(const float* __restrict__ Wd, const float* __restrict__ Wu,
                          const float* __restrict__ Wg,
                          u16* __restrict__ wd_pack, u16* __restrict__ wu_pack) {
  int idx = blockIdx.x * 256 + threadIdx.x;
  if (idx < WD_ELEMS) {
    int frag = idx >> 9, w = idx & 511;
    int lane = w >> 3, j = w & 7;
    int nt = frag >> 5, kt = frag & 31;
    int k = kt * 32 + (lane >> 4) * 8 + j;        // 0..1023
    int col = nt * 16 + (lane & 15);              // 0..271
    float v;
    if (col < 256) {
      v = Wd[((col >> 6) * 1024 + k) * 64 + (col & 63)];   // W_down[e][k][a]
    } else {
      int c2 = col - 256;
      v = (c2 < 4) ? Wg[k * 4 + c2] : 0.f;                 // W_gate[k][e], zero-padded
    }
    wd_pack[idx] = f2bf(v);
  } else if (idx < WD_ELEMS + WU_ELEMS) {
    int u = idx - WD_ELEMS;
    int frag = u >> 9, w = u & 511;
    int lane = w >> 3, j = w & 7;
    int nt = frag >> 3, kt = frag & 7;
    int k = kt * 32 + (lane >> 4) * 8 + j;        // 0..255 (= e*64 + a)
    int col = nt * 16 + (lane & 15);              // 0..1023
    wu_pack[u] = f2bf(Wu[((k >> 6) * 64 + (k & 63)) * 1024 + col]);  // W_up[e][a][d]
  }
}

// LDS chunk tile: [32 rows][256 k] bf16, row stride 512 B, XOR-swizzled:
// byte = row*512 + (2*k ^ ((row&7)<<4))  -> ds_read_b128 A-frags are ~2-way (free).
__device__ __forceinline__ void pack_store(char* dst, int r, int col, float4 v0, float4 v1) {
  bf16x8 h;
  h[0] = (short)f2bf(v0.x); h[1] = (short)f2bf(v0.y);
  h[2] = (short)f2bf(v0.z); h[3] = (short)f2bf(v0.w);
  h[4] = (short)f2bf(v1.x); h[5] = (short)f2bf(v1.y);
  h[6] = (short)f2bf(v1.z); h[7] = (short)f2bf(v1.w);
  int cb = col * 2;
  *(bf16x8*)(dst + r * 512 + (cb ^ ((r & 7) << 4))) = h;
}

__global__ __launch_bounds__(256, 2) void lora_main(
    const float* __restrict__ x, const float* __restrict__ b_gate,
    const u16* __restrict__ wd_pack, const u16* __restrict__ wu_pack,
    float* __restrict__ out) {
  extern __shared__ char smem[];
  float* g = (float*)(smem + 32768);

  const int tid = threadIdx.x;
  const int lane = tid & 63;
  const int wave = tid >> 6;       // 4 waves
  const int l15 = lane & 15;
  const int lg = lane >> 4;
  const size_t row0 = (size_t)blockIdx.x * ROWS;
  const float* xblk = x + row0 * D_MODEL;

  f32x4 acc[4][2];   // [col-tile i][row-frag r]; wave w owns tiles {w, w+4, w+8, w+12}
  f32x4 accg[2];     // gate tile (nt=16), wave 3 only
#pragma unroll
  for (int i = 0; i < 4; ++i)
#pragma unroll
    for (int r = 0; r < 2; ++r) acc[i][r] = {0.f, 0.f, 0.f, 0.f};
#pragma unroll
  for (int r = 0; r < 2; ++r) accg[r] = {0.f, 0.f, 0.f, 0.f};

  // ---- prologue: stage K-chunk 0 into buf0 (fp32 -> bf16, swizzled)
  {
    const float* src = xblk;
#pragma unroll
    for (int it = 0; it < 4; ++it) {
      int flat = it * 2048 + tid * 8;        // 32 rows x 256 cols = 8192 floats
      int r = flat >> 8, col = flat & 255;
      float4 v0 = *(const float4*)(src + r * D_MODEL + col);
      float4 v1 = *(const float4*)(src + r * D_MODEL + col + 4);
      pack_store(smem, r, col, v0, v1);
    }
  }
  __syncthreads();

  // ---- phase 1: down[32][256] (+gate logits), K = 1024 in 4 chunks of 256
  float4 pre[8];
#pragma unroll 1
  for (int c = 0; c < 4; ++c) {
    if (c < 3) {  // T14 split: issue next chunk's global loads before compute
      const float* src = xblk + (c + 1) * 256;
#pragma unroll
      for (int it = 0; it < 4; ++it) {
        int flat = it * 2048 + tid * 8;
        int r = flat >> 8, col = flat & 255;
        pre[2 * it]     = *(const float4*)(src + r * D_MODEL + col);
        pre[2 * it + 1] = *(const float4*)(src + r * D_MODEL + col + 4);
      }
    }
    const char* buf = smem + (c & 1) * 16384;
#pragma unroll
    for (int ks = 0; ks < 8; ++ks) {
      const int ktg = c * 8 + ks;
      bf16x8 a[2];
#pragma unroll
      for (int r = 0; r < 2; ++r) {
        int rr = r * 16 + l15;
        int cb = (ks * 32 + lg * 8) * 2;
        a[r] = *(const bf16x8*)(buf + rr * 512 + (cb ^ ((rr & 7) << 4)));
      }
#pragma unroll
      for (int i = 0; i < 4; ++i) {
        const int nt = wave + i * 4;
        bf16x8 b = *(const bf16x8*)(wd_pack + (size_t)(nt * 32 + ktg) * 512 + lane * 8);
#pragma unroll
        for (int r = 0; r < 2; ++r)
          acc[i][r] = __builtin_amdgcn_mfma_f32_16x16x32_bf16(a[r], b, acc[i][r], 0, 0, 0);
      }
      if (wave == 3) {  // gate tile nt=16 -> frag base 16*32 = 512
        bf16x8 b = *(const bf16x8*)(wd_pack + (size_t)(512 + ktg) * 512 + lane * 8);
#pragma unroll
        for (int r = 0; r < 2; ++r)
          accg[r] = __builtin_amdgcn_mfma_f32_16x16x32_bf16(a[r], b, accg[r], 0, 0, 0);
      }
    }
    if (c < 3) {  // write-late: convert + ds_write into the other buffer
      char* dst = smem + ((c + 1) & 1) * 16384;
#pragma unroll
      for (int it = 0; it < 4; ++it) {
        int flat = it * 2048 + tid * 8;
        int r = flat >> 8, col = flat & 255;
        pack_store(dst, r, col, pre[2 * it], pre[2 * it + 1]);
      }
    }
    __syncthreads();
  }

  // ---- gate softmax (fp32). C-layout: col=lane&15, row=(lane>>4)*4+reg.
  if (wave == 3 && l15 < 4) {
#pragma unroll
    for (int r = 0; r < 2; ++r)
#pragma unroll
      for (int j = 0; j < 4; ++j)
        g[(r * 16 + lg * 4 + j) * 4 + l15] = accg[r][j];
  }
  __syncthreads();
  if (tid < ROWS) {
    float v0 = g[tid * 4 + 0] + b_gate[0];
    float v1 = g[tid * 4 + 1] + b_gate[1];
    float v2 = g[tid * 4 + 2] + b_gate[2];
    float v3 = g[tid * 4 + 3] + b_gate[3];
    float m = fmaxf(fmaxf(v0, v1), fmaxf(v2, v3));
    float e0 = expf(v0 - m), e1 = expf(v1 - m), e2 = expf(v2 - m), e3 = expf(v3 - m);
    float inv = 1.f / (e0 + e1 + e2 + e3);
    g[tid * 4 + 0] = e0 * inv; g[tid * 4 + 1] = e1 * inv;
    g[tid * 4 + 2] = e2 * inv; g[tid * 4 + 3] = e3 * inv;
  }
  __syncthreads();

  // ---- apply gate, pack down to bf16 into buf0 (same swizzled layout, k=ea)
  char* ds = smem;
#pragma unroll
  for (int i = 0; i < 4; ++i) {
    int nt = wave + i * 4;
    int col = nt * 16 + l15;
    int e = nt >> 2;              // 4 col-tiles per expert
    int cb = col * 2;
#pragma unroll
    for (int r = 0; r < 2; ++r) {
#pragma unroll
      for (int j = 0; j < 4; ++j) {
        int row = r * 16 + lg * 4 + j;
        float val = acc[i][r][j] * g[row * 4 + e];
        *(u16*)(ds + row * 512 + (cb ^ ((row & 7) << 4))) = f2bf(val);
      }
    }
  }
  __syncthreads();

  // ---- phase 2: out[32][1024] = down_g[32][256] @ Wup, N in 4 chunks of 256.
  // Epilogue transposes through tb (aliases buf1+g, both dead; DISJOINT from ds)
  // so each wave stores contiguous 1 KB float4 runs.
  float* tb = (float*)(smem + 16384);
#pragma unroll 1
  for (int nc = 0; nc < 4; ++nc) {
    f32x4 acc2[4][2];
#pragma unroll
    for (int i = 0; i < 4; ++i)
#pragma unroll
      for (int r = 0; r < 2; ++r) acc2[i][r] = {0.f, 0.f, 0.f, 0.f};
#pragma unroll
    for (int ks = 0; ks < 8; ++ks) {
      bf16x8 a[2];
#pragma unroll
      for (int r = 0; r < 2; ++r) {
        int rr = r * 16 + l15;
        int cb = (ks * 32 + lg * 8) * 2;
        a[r] = *(const bf16x8*)(ds + rr * 512 + (cb ^ ((rr & 7) << 4)));
      }
#pragma unroll
      for (int i = 0; i < 4; ++i) {
        int ntu = nc * 16 + wave * 4 + i;
        bf16x8 b = *(const bf16x8*)(wu_pack + (size_t)(ntu * 8 + ks) * 512 + lane * 8);
#pragma unroll
        for (int r = 0; r < 2; ++r)
          acc2[i][r] = __builtin_amdgcn_mfma_f32_16x16x32_bf16(a[r], b, acc2[i][r], 0, 0, 0);
      }
    }
#pragma unroll
    for (int i = 0; i < 4; ++i) {
      int cl = wave * 64 + i * 16 + l15;    // col within this 256-col chunk
#pragma unroll
      for (int r = 0; r < 2; ++r)
#pragma unroll
        for (int j = 0; j < 4; ++j)
          tb[(r * 16 + lg * 4 + j) * TB_STRIDE + cl] = acc2[i][r][j];
    }
    __syncthreads();
#pragma unroll
    for (int it = 0; it < 8; ++it) {
      int flat = it * 1024 + tid * 4;       // 32 rows x 256 cols f32
      int row = flat >> 8, col = flat & 255;
      float4 v = *(const float4*)(tb + row * TB_STRIDE + col);
      *(float4*)(out + (row0 + row) * D_MODEL + nc * 256 + col) = v;
    }
    __syncthreads();
  }
}

extern "C" void kernel_launch(void* const* d_in, const int* in_sizes, int n_in,
                              void* d_out, int out_size, void* d_ws, size_t ws_size,
                              hipStream_t stream) {
  const float* x  = (const float*)d_in[0];
  const float* Wd = (const float*)d_in[1];
  const float* Wu = (const float*)d_in[2];
  const float* Wg = (const float*)d_in[3];
  const float* bg = (const float*)d_in[4];
  float* out = (float*)d_out;
  const int M = in_sizes[0] / D_MODEL;  // 16384

  u16* wd_pack = (u16*)d_ws;            // 557056 B
  u16* wu_pack = wd_pack + WD_ELEMS;    // +524288 B  (needs ~1.03 MB of ws)

  const int total = WD_ELEMS + WU_ELEMS;
  lora_prep<<<(total + 255) / 256, 256, 0, stream>>>(Wd, Wu, Wg, wd_pack, wu_pack);
  lora_main<<<M / ROWS, 256, LDS_TOTAL, stream>>>(x, bg, wd_pack, wu_pack, out);
}

// Round 5
// 51.331 us; speedup vs baseline: 2.4667x; 1.4279x over previous
//
#include <hip/hip_runtime.h>

typedef __attribute__((ext_vector_type(8))) short bf16x8;
typedef __attribute__((ext_vector_type(4))) float f32x4;
typedef unsigned short u16;

#define D_MODEL 1024
#define ROWS 32            // rows per block: grid 512, 2 blocks/CU, 8 waves each

// Packed-weight geometry: fragments of 512 bf16 (64 lanes x 8), frag(nt,kt).
// Phase-1 B: 17 col-tiles (16 down + 1 gate-padded) x 32 k-tiles (K=1024).
// Phase-2 B: 64 col-tiles (N=1024)                x  8 k-tiles (K=256).
#define WD_FRAGS (17 * 32)
#define WU_FRAGS (64 * 8)
#define WD_ELEMS (WD_FRAGS * 512)   // 278528 bf16
#define WU_ELEMS (WU_FRAGS * 512)   // 262144 bf16

// LDS map (bytes), total 49664:
//  phase 1: buf0 [0,16384) | buf1 [16384,32768) | g[32][4] f32 [32768,33280)
//  phase 2: ds (gated-down, 32x512B) = buf0 [0,16384)
//           tb (transpose, 32x260 f32 = 33280 B) = [16384,49664)  (buf1+g dead)
// tb 4-row group stride = 4*260*4 B ≡ 16 words mod 32 banks -> scatter is 2-way (free).
#define LDS_TOTAL 49664
#define TB_STRIDE 260

__device__ __forceinline__ u16 f2bf(float f) {  // RNE f32 -> bf16
  union { float f; unsigned u; } v; v.f = f;
  return (u16)((v.u + 0x7fffu + ((v.u >> 16) & 1u)) >> 16);
}

// Pack per-expert weights into MFMA B-fragment order (bf16).
// Fragment element (lane, j) holds B[k = kt*32 + (lane>>4)*8 + j][col = nt*16 + (lane&15)].
__global__ void lora_prep(const float* __restrict__ Wd, const float* __restrict__ Wu,
                          const float* __restrict__ Wg,
                          u16* __restrict__ wd_pack, u16* __restrict__ wu_pack) {
  int idx = blockIdx.x * 256 + threadIdx.x;
  if (idx < WD_ELEMS) {
    int frag = idx >> 9, w = idx & 511;
    int lane = w >> 3, j = w & 7;
    int nt = frag >> 5, kt = frag & 31;
    int k = kt * 32 + (lane >> 4) * 8 + j;        // 0..1023
    int col = nt * 16 + (lane & 15);              // 0..271
    float v;
    if (col < 256) {
      v = Wd[((col >> 6) * 1024 + k) * 64 + (col & 63)];   // W_down[e][k][a]
    } else {
      int c2 = col - 256;
      v = (c2 < 4) ? Wg[k * 4 + c2] : 0.f;                 // W_gate[k][e], zero-padded
    }
    wd_pack[idx] = f2bf(v);
  } else if (idx < WD_ELEMS + WU_ELEMS) {
    int u = idx - WD_ELEMS;
    int frag = u >> 9, w = u & 511;
    int lane = w >> 3, j = w & 7;
    int nt = frag >> 3, kt = frag & 7;
    int k = kt * 32 + (lane >> 4) * 8 + j;        // 0..255 (= e*64 + a)
    int col = nt * 16 + (lane & 15);              // 0..1023
    wu_pack[u] = f2bf(Wu[((k >> 6) * 64 + (k & 63)) * 1024 + col]);  // W_up[e][a][d]
  }
}

// LDS chunk tile: [32 rows][256 k] bf16, row stride 512 B, XOR-swizzled:
// byte = row*512 + (2*k ^ ((row&7)<<4))  -> ds_read_b128 A-frags are ~2-way (free).
__device__ __forceinline__ void pack_store(char* dst, int r, int col, float4 v0, float4 v1) {
  bf16x8 h;
  h[0] = (short)f2bf(v0.x); h[1] = (short)f2bf(v0.y);
  h[2] = (short)f2bf(v0.z); h[3] = (short)f2bf(v0.w);
  h[4] = (short)f2bf(v1.x); h[5] = (short)f2bf(v1.y);
  h[6] = (short)f2bf(v1.z); h[7] = (short)f2bf(v1.w);
  int cb = col * 2;
  *(bf16x8*)(dst + r * 512 + (cb ^ ((r & 7) << 4))) = h;
}

__global__ __launch_bounds__(512, 4) void lora_main(
    const float* __restrict__ x, const float* __restrict__ b_gate,
    const u16* __restrict__ wd_pack, const u16* __restrict__ wu_pack,
    float* __restrict__ out) {
  extern __shared__ char smem[];
  float* g = (float*)(smem + 32768);

  const int tid = threadIdx.x;     // 0..511
  const int lane = tid & 63;
  const int wave = tid >> 6;       // 0..7
  const int l15 = lane & 15;
  const int lg = lane >> 4;
  const size_t row0 = (size_t)blockIdx.x * ROWS;
  const float* xblk = x + row0 * D_MODEL;

  f32x4 acc[2][2];   // [col-tile i][row-frag r]; wave w owns tiles {w, w+8}
  f32x4 accg[2];     // gate tile (nt=16), wave 7 only
#pragma unroll
  for (int i = 0; i < 2; ++i)
#pragma unroll
    for (int r = 0; r < 2; ++r) acc[i][r] = {0.f, 0.f, 0.f, 0.f};
#pragma unroll
  for (int r = 0; r < 2; ++r) accg[r] = {0.f, 0.f, 0.f, 0.f};

  // ---- prologue: stage K-chunk 0 into buf0 (fp32 -> bf16, swizzled)
#pragma unroll
  for (int it = 0; it < 2; ++it) {
    int flat = it * 4096 + tid * 8;          // 32 rows x 256 cols = 8192 floats
    int r = flat >> 8, col = flat & 255;
    float4 v0 = *(const float4*)(xblk + r * D_MODEL + col);
    float4 v1 = *(const float4*)(xblk + r * D_MODEL + col + 4);
    pack_store(smem, r, col, v0, v1);
  }
  __syncthreads();

  // ---- phase 1: down[32][256] (+gate logits), K = 1024 in 4 chunks of 256.
  // B fragments prefetched depth-2 (bq slot = ks % 3, all indices static after unroll).
  float4 pre[4];
  bf16x8 bq[3][2];
  bf16x8 gq[3];
#pragma unroll 1
  for (int c = 0; c < 4; ++c) {
    if (c < 3) {  // T14 split: issue next chunk's global loads before compute
      const float* src = xblk + (c + 1) * 256;
#pragma unroll
      for (int it = 0; it < 2; ++it) {
        int flat = it * 4096 + tid * 8;
        int r = flat >> 8, col = flat & 255;
        pre[2 * it]     = *(const float4*)(src + r * D_MODEL + col);
        pre[2 * it + 1] = *(const float4*)(src + r * D_MODEL + col + 4);
      }
    }
    const char* buf = smem + (c & 1) * 16384;
    // preload B for ks = 0,1
#pragma unroll
    for (int pk = 0; pk < 2; ++pk) {
      int ktg = c * 8 + pk;
#pragma unroll
      for (int i = 0; i < 2; ++i)
        bq[pk][i] = *(const bf16x8*)(wd_pack + (size_t)((wave + i * 8) * 32 + ktg) * 512 + lane * 8);
      if (wave == 7)
        gq[pk] = *(const bf16x8*)(wd_pack + (size_t)(512 + ktg) * 512 + lane * 8);
    }
#pragma unroll
    for (int ks = 0; ks < 8; ++ks) {
      const int s = ks % 3;
      if (ks < 6) {  // prefetch ks+2
        int ktg2 = c * 8 + ks + 2;
        int s2 = (ks + 2) % 3;
#pragma unroll
        for (int i = 0; i < 2; ++i)
          bq[s2][i] = *(const bf16x8*)(wd_pack + (size_t)((wave + i * 8) * 32 + ktg2) * 512 + lane * 8);
        if (wave == 7)
          gq[s2] = *(const bf16x8*)(wd_pack + (size_t)(512 + ktg2) * 512 + lane * 8);
      }
      bf16x8 a[2];
#pragma unroll
      for (int r = 0; r < 2; ++r) {
        int rr = r * 16 + l15;
        int cb = (ks * 32 + lg * 8) * 2;
        a[r] = *(const bf16x8*)(buf + rr * 512 + (cb ^ ((rr & 7) << 4)));
      }
#pragma unroll
      for (int i = 0; i < 2; ++i)
#pragma unroll
        for (int r = 0; r < 2; ++r)
          acc[i][r] = __builtin_amdgcn_mfma_f32_16x16x32_bf16(a[r], bq[s][i], acc[i][r], 0, 0, 0);
      if (wave == 7) {
#pragma unroll
        for (int r = 0; r < 2; ++r)
          accg[r] = __builtin_amdgcn_mfma_f32_16x16x32_bf16(a[r], gq[s], accg[r], 0, 0, 0);
      }
    }
    if (c < 3) {  // write-late: convert + ds_write into the other buffer
      char* dst = smem + ((c + 1) & 1) * 16384;
#pragma unroll
      for (int it = 0; it < 2; ++it) {
        int flat = it * 4096 + tid * 8;
        int r = flat >> 8, col = flat & 255;
        pack_store(dst, r, col, pre[2 * it], pre[2 * it + 1]);
      }
    }
    __syncthreads();
  }

  // ---- gate softmax (fp32). C-layout: col=lane&15, row=(lane>>4)*4+reg.
  if (wave == 7 && l15 < 4) {
#pragma unroll
    for (int r = 0; r < 2; ++r)
#pragma unroll
      for (int j = 0; j < 4; ++j)
        g[(r * 16 + lg * 4 + j) * 4 + l15] = accg[r][j];
  }
  __syncthreads();
  if (tid < ROWS) {
    float v0 = g[tid * 4 + 0] + b_gate[0];
    float v1 = g[tid * 4 + 1] + b_gate[1];
    float v2 = g[tid * 4 + 2] + b_gate[2];
    float v3 = g[tid * 4 + 3] + b_gate[3];
    float m = fmaxf(fmaxf(v0, v1), fmaxf(v2, v3));
    float e0 = expf(v0 - m), e1 = expf(v1 - m), e2 = expf(v2 - m), e3 = expf(v3 - m);
    float inv = 1.f / (e0 + e1 + e2 + e3);
    g[tid * 4 + 0] = e0 * inv; g[tid * 4 + 1] = e1 * inv;
    g[tid * 4 + 2] = e2 * inv; g[tid * 4 + 3] = e3 * inv;
  }
  __syncthreads();

  // ---- apply gate, pack down to bf16 into buf0 (same swizzled layout, k=e*64+a)
  char* ds = smem;
#pragma unroll
  for (int i = 0; i < 2; ++i) {
    int nt = wave + i * 8;
    int col = nt * 16 + l15;
    int e = nt >> 2;              // 4 col-tiles per expert
    int cb = col * 2;
#pragma unroll
    for (int r = 0; r < 2; ++r) {
#pragma unroll
      for (int j = 0; j < 4; ++j) {
        int row = r * 16 + lg * 4 + j;
        float val = acc[i][r][j] * g[row * 4 + e];
        *(u16*)(ds + row * 512 + (cb ^ ((row & 7) << 4))) = f2bf(val);
      }
    }
  }
  __syncthreads();

  // ---- phase 2: out[32][1024] = down_g[32][256] @ Wup, N in 4 chunks of 256.
  // Epilogue transposes through tb (aliases buf1+g, both dead; DISJOINT from ds)
  // so each wave stores contiguous 1 KB float4 runs.
  float* tb = (float*)(smem + 16384);
  bf16x8 b2[3][2];
#pragma unroll 1
  for (int nc = 0; nc < 4; ++nc) {
    f32x4 acc2[2][2];
#pragma unroll
    for (int i = 0; i < 2; ++i)
#pragma unroll
      for (int r = 0; r < 2; ++r) acc2[i][r] = {0.f, 0.f, 0.f, 0.f};
    // preload B for ks = 0,1
#pragma unroll
    for (int pk = 0; pk < 2; ++pk)
#pragma unroll
      for (int i = 0; i < 2; ++i)
        b2[pk][i] = *(const bf16x8*)(wu_pack + (size_t)((nc * 16 + wave * 2 + i) * 8 + pk) * 512 + lane * 8);
#pragma unroll
    for (int ks = 0; ks < 8; ++ks) {
      const int s = ks % 3;
      if (ks < 6) {  // prefetch ks+2
        int s2 = (ks + 2) % 3;
#pragma unroll
        for (int i = 0; i < 2; ++i)
          b2[s2][i] = *(const bf16x8*)(wu_pack + (size_t)((nc * 16 + wave * 2 + i) * 8 + ks + 2) * 512 + lane * 8);
      }
      bf16x8 a[2];
#pragma unroll
      for (int r = 0; r < 2; ++r) {
        int rr = r * 16 + l15;
        int cb = (ks * 32 + lg * 8) * 2;
        a[r] = *(const bf16x8*)(ds + rr * 512 + (cb ^ ((rr & 7) << 4)));
      }
#pragma unroll
      for (int i = 0; i < 2; ++i)
#pragma unroll
        for (int r = 0; r < 2; ++r)
          acc2[i][r] = __builtin_amdgcn_mfma_f32_16x16x32_bf16(a[r], b2[s][i], acc2[i][r], 0, 0, 0);
    }
#pragma unroll
    for (int i = 0; i < 2; ++i) {
      int cl = wave * 32 + i * 16 + l15;    // col within this 256-col chunk
#pragma unroll
      for (int r = 0; r < 2; ++r)
#pragma unroll
        for (int j = 0; j < 4; ++j)
          tb[(r * 16 + lg * 4 + j) * TB_STRIDE + cl] = acc2[i][r][j];
    }
    __syncthreads();
#pragma unroll
    for (int it = 0; it < 4; ++it) {
      int flat = it * 2048 + tid * 4;       // 32 rows x 256 cols f32
      int row = flat >> 8, col = flat & 255;
      float4 v = *(const float4*)(tb + row * TB_STRIDE + col);
      *(float4*)(out + (row0 + row) * D_MODEL + nc * 256 + col) = v;
    }
    __syncthreads();
  }
}

extern "C" void kernel_launch(void* const* d_in, const int* in_sizes, int n_in,
                              void* d_out, int out_size, void* d_ws, size_t ws_size,
                              hipStream_t stream) {
  const float* x  = (const float*)d_in[0];
  const float* Wd = (const float*)d_in[1];
  const float* Wu = (const float*)d_in[2];
  const float* Wg = (const float*)d_in[3];
  const float* bg = (const float*)d_in[4];
  float* out = (float*)d_out;
  const int M = in_sizes[0] / D_MODEL;  // 16384

  u16* wd_pack = (u16*)d_ws;            // 557056 B
  u16* wu_pack = wd_pack + WD_ELEMS;    // +524288 B  (needs ~1.03 MB of ws)

  const int total = WD_ELEMS + WU_ELEMS;
  lora_prep<<<(total + 255) / 256, 256, 0, stream>>>(Wd, Wu, Wg, wd_pack, wu_pack);
  lora_main<<<M / ROWS, 512, LDS_TOTAL, stream>>>(x, bg, wd_pack, wu_pack, out);
}